// Round 2
// baseline (222.464 us; speedup 1.0000x reference)
//
#include <hip/hip_runtime.h>
#include <math.h>

#define T_TOK 8192
#define A_DIM 1024
#define E_DIM 512
#define S_SPAN 32768
#define HID 150

typedef __attribute__((ext_vector_type(8))) short short8;
typedef __attribute__((ext_vector_type(4))) float f32x4;
typedef __attribute__((ext_vector_type(4))) unsigned int u32x4;

__device__ __forceinline__ unsigned short f2bf(float f) {
    unsigned int u = __builtin_bit_cast(unsigned int, f);
    u += 0x7FFFu + ((u >> 16) & 1u);          // RNE
    return (unsigned short)(u >> 16);
}
__device__ __forceinline__ float bf2f(unsigned int h16) {
    unsigned int u = h16 << 16;
    return __builtin_bit_cast(float, u);
}
__device__ __forceinline__ short8 cast8(f32x4 a, f32x4 b) {
    short8 r;
    r[0] = (short)f2bf(a.x); r[1] = (short)f2bf(a.y);
    r[2] = (short)f2bf(a.z); r[3] = (short)f2bf(a.w);
    r[4] = (short)f2bf(b.x); r[5] = (short)f2bf(b.y);
    r[6] = (short)f2bf(b.z); r[7] = (short)f2bf(b.w);
    return r;
}

// ---------------------------------------------------------------------------
// prep: 6 weight transposes + width projection (+bs1 folded, zero-padded 160)
// ---------------------------------------------------------------------------
struct WConv { const float* src; unsigned short* dst; int K0; int Kpad; int nblk; };
struct PrepTab {
    WConv g[6];
    const float* wt; const float* Ws1w; const float* bs1; float* PW;
};

__global__ __launch_bounds__(256) void prep_kernel(PrepTab tab) {
    int b = blockIdx.x;
    #pragma unroll
    for (int gi = 0; gi < 6; ++gi) {
        if (b < tab.g[gi].nblk) {
            int idx = b * 256 + threadIdx.x;               // idx = k*160 + j
            int Kpad = tab.g[gi].Kpad;
            if (idx < Kpad * 160) {
                int k = idx / 160, j = idx - k * 160;
                float v = (j < HID && k < tab.g[gi].K0)
                          ? tab.g[gi].src[(size_t)k * HID + j] : 0.f;   // coalesced read
                tab.g[gi].dst[(size_t)j * Kpad + k] = f2bf(v);          // scattered write
            }
            return;
        }
        b -= tab.g[gi].nblk;
    }
    // width projection: 9 blocks. PW row = width_table[b] @ Ws1w + bs1,
    // stride 160 with exact zeros at j>=150 (GEMM K-pad for span_fused).
    int j = threadIdx.x;
    if (j < 160) {
        float acc = 0.f;
        if (j < HID) {
            for (int k = 0; k < 20; ++k)
                acc = fmaf(tab.wt[b * 20 + k], tab.Ws1w[k * HID + j], acc);
            acc += tab.bs1[j];
        }
        tab.PW[b * 160 + j] = acc;
    }
}

// ---------------------------------------------------------------------------
// unified MFMA GEMM, 2-deep pipelined K-loop (this round's change).
// At chunk c: issue global loads for chunk c+2 (W and A, into the reg set
// freed when chunk c went to LDS), ds_write chunk c+1 (its loads were issued
// a FULL chunk ago -> vmcnt already satisfied, no stall), MFMA chunk c.
// Same barrier count and bit-identical accumulation order as the 1-deep loop.
// W2 path — fused attn layer2+3 in group-0 epilogue (unchanged).
// ---------------------------------------------------------------------------
struct GG {
    const void* A; int lda;
    const unsigned short* W; int K; int nrb;
    unsigned short* outh; int ldo;
    const float* bias; int relu;
    const float* dotv; const float* dotb; float* dotout;
    const unsigned short* W2; const float* bias2;
};
struct GTab { GG g[4]; int ng; };

template <int TAG, bool AF32>
__global__ __launch_bounds__(256) void gemm_fused(GTab tab) {
    constexpr int LDW = 72;
    __shared__ unsigned short WtL[2][160 * LDW];

    int b = blockIdx.x;
    int gi = 0;
    while (gi < tab.ng - 1 && b >= tab.g[gi].nrb) { b -= tab.g[gi].nrb; ++gi; }
    const GG G = tab.g[gi];

    const int tid = threadIdx.x;
    const int wid = tid >> 6;
    const int lane = tid & 63;
    const int l15 = lane & 15;
    const int quad = lane >> 4;
    const int row0 = b * 64 + wid * 16 + l15;
    const int K = G.K;
    const int nch = K >> 6;
    const float* Af = (const float*)G.A + (size_t)row0 * G.lda;
    const unsigned short* Ah = (const unsigned short*)G.A + (size_t)row0 * G.lda;

    int sn[5], sk[5];
    #pragma unroll
    for (int i = 0; i < 5; ++i) { int u = tid + i * 256; sn[i] = u >> 3; sk[i] = (u & 7) * 8; }

    f32x4 acc[10];
    #pragma unroll
    for (int nt = 0; nt < 10; ++nt) acc[nt] = (f32x4){0.f, 0.f, 0.f, 0.f};

    // chunk k lives in reg set k&1.
    u32x4 stg[2][5];
    f32x4 fA[2][4];
    short8 hA[2][2];
    short8 avc0, avc1;

    // ---- prologue: issue chunk 0 AND chunk 1 loads before any wait ----
    #pragma unroll
    for (int i = 0; i < 5; ++i)
        stg[0][i] = *(const u32x4*)(G.W + (size_t)sn[i] * K + sk[i]);
    if (AF32) {
        fA[0][0] = *(const f32x4*)(Af + quad * 8);
        fA[0][1] = *(const f32x4*)(Af + quad * 8 + 4);
        fA[0][2] = *(const f32x4*)(Af + 32 + quad * 8);
        fA[0][3] = *(const f32x4*)(Af + 32 + quad * 8 + 4);
    } else {
        hA[0][0] = *(const short8*)(Ah + quad * 8);
        hA[0][1] = *(const short8*)(Ah + 32 + quad * 8);
    }
    if (nch > 1) {
        #pragma unroll
        for (int i = 0; i < 5; ++i)
            stg[1][i] = *(const u32x4*)(G.W + (size_t)sn[i] * K + 64 + sk[i]);
        if (AF32) {
            fA[1][0] = *(const f32x4*)(Af + 64 + quad * 8);
            fA[1][1] = *(const f32x4*)(Af + 64 + quad * 8 + 4);
            fA[1][2] = *(const f32x4*)(Af + 96 + quad * 8);
            fA[1][3] = *(const f32x4*)(Af + 96 + quad * 8 + 4);
        } else {
            hA[1][0] = *(const short8*)(Ah + 64 + quad * 8);
            hA[1][1] = *(const short8*)(Ah + 96 + quad * 8);
        }
    }
    // stage chunk 0 to LDS (one-time vmcnt stall; chunk-1 loads stay in flight)
    #pragma unroll
    for (int i = 0; i < 5; ++i)
        *(u32x4*)&WtL[0][sn[i] * LDW + sk[i]] = stg[0][i];
    if (AF32) { avc0 = cast8(fA[0][0], fA[0][1]); avc1 = cast8(fA[0][2], fA[0][3]); }
    else      { avc0 = hA[0][0];                  avc1 = hA[0][1]; }
    __syncthreads();

    for (int c = 0; c < nch; ++c) {
        const int pb = c & 1;
        const bool m1 = (c + 1 < nch);
        const bool m2 = (c + 2 < nch);
        if (m2) {
            const int kn = (c + 2) << 6;
            #pragma unroll
            for (int i = 0; i < 5; ++i)
                stg[pb][i] = *(const u32x4*)(G.W + (size_t)sn[i] * K + kn + sk[i]);
            if (AF32) {
                fA[pb][0] = *(const f32x4*)(Af + kn + quad * 8);
                fA[pb][1] = *(const f32x4*)(Af + kn + quad * 8 + 4);
                fA[pb][2] = *(const f32x4*)(Af + kn + 32 + quad * 8);
                fA[pb][3] = *(const f32x4*)(Af + kn + 32 + quad * 8 + 4);
            } else {
                hA[pb][0] = *(const short8*)(Ah + kn + quad * 8);
                hA[pb][1] = *(const short8*)(Ah + kn + 32 + quad * 8);
            }
        }
        if (m1) {
            // chunk c+1 data: loaded at iteration c-1 (or prologue) -> no stall
            #pragma unroll
            for (int i = 0; i < 5; ++i)
                *(u32x4*)&WtL[pb ^ 1][sn[i] * LDW + sk[i]] = stg[pb ^ 1][i];
        }
        #pragma unroll
        for (int nt = 0; nt < 10; ++nt) {
            short8 bv0 = *(const short8*)&WtL[pb][(nt * 16 + l15) * LDW + quad * 8];
            acc[nt] = __builtin_amdgcn_mfma_f32_16x16x32_bf16(avc0, bv0, acc[nt], 0, 0, 0);
            short8 bv1 = *(const short8*)&WtL[pb][(nt * 16 + l15) * LDW + 32 + quad * 8];
            acc[nt] = __builtin_amdgcn_mfma_f32_16x16x32_bf16(avc1, bv1, acc[nt], 0, 0, 0);
        }
        if (m1) {
            if (AF32) { avc0 = cast8(fA[pb ^ 1][0], fA[pb ^ 1][1]); avc1 = cast8(fA[pb ^ 1][2], fA[pb ^ 1][3]); }
            else      { avc0 = hA[pb ^ 1][0];                        avc1 = hA[pb ^ 1][1]; }
        }
        __syncthreads();
    }

    const int rbase = b * 64 + wid * 16 + quad * 4;
    if (G.W2) {
        // ---- fused attn layer2+3 ----
        constexpr int LDH = 168;
        unsigned short* tile = &WtL[0][0] + wid * 16 * LDH;   // per-wave region
        #pragma unroll
        for (int nt = 0; nt < 10; ++nt) {
            int col = nt * 16 + l15;
            float bv_ = (col < HID) ? G.bias[col] : 0.f;
            #pragma unroll
            for (int r = 0; r < 4; ++r) {
                float v = fmaxf(acc[nt][r] + bv_, 0.f);
                tile[(quad * 4 + r) * LDH + col] = f2bf(v);
            }
        }
        // same-wave RAW through LDS: compiler inserts lgkmcnt; no barrier.
        f32x4 acc2[10];
        #pragma unroll
        for (int nt = 0; nt < 10; ++nt) acc2[nt] = (f32x4){0.f, 0.f, 0.f, 0.f};
        #pragma unroll
        for (int kc = 0; kc < 5; ++kc) {
            short8 av = *(const short8*)&tile[l15 * LDH + kc * 32 + quad * 8];
            #pragma unroll
            for (int nt = 0; nt < 10; ++nt) {
                short8 bv = *(const short8*)(G.W2 + (size_t)(nt * 16 + l15) * 192 + kc * 32 + quad * 8);
                acc2[nt] = __builtin_amdgcn_mfma_f32_16x16x32_bf16(av, bv, acc2[nt], 0, 0, 0);
            }
        }
        float part[4] = {0.f, 0.f, 0.f, 0.f};
        #pragma unroll
        for (int nt = 0; nt < 10; ++nt) {
            int col = nt * 16 + l15;
            float b2 = (col < HID) ? G.bias2[col] : 0.f;
            float vv = (col < HID) ? G.dotv[col] : 0.f;
            #pragma unroll
            for (int r = 0; r < 4; ++r)
                part[r] += fmaxf(acc2[nt][r] + b2, 0.f) * vv;
        }
        #pragma unroll
        for (int r = 0; r < 4; ++r) {
            float p = part[r];
            #pragma unroll
            for (int off = 1; off < 16; off <<= 1) p += __shfl_xor(p, off);
            if (l15 == 0) G.dotout[rbase + r] = p + G.dotb[0];
        }
    } else if (G.dotout) {
        float part[4] = {0.f, 0.f, 0.f, 0.f};
        #pragma unroll
        for (int nt = 0; nt < 10; ++nt) {
            int col = nt * 16 + l15;
            float bv_ = (col < HID) ? G.bias[col] : 0.f;
            float vv = (col < HID) ? G.dotv[col] : 0.f;
            #pragma unroll
            for (int r = 0; r < 4; ++r)
                part[r] += fmaxf(acc[nt][r] + bv_, 0.f) * vv;
        }
        #pragma unroll
        for (int r = 0; r < 4; ++r) {
            float p = part[r];
            #pragma unroll
            for (int off = 1; off < 16; off <<= 1) p += __shfl_xor(p, off);
            if (l15 == 0) G.dotout[rbase + r] = p + G.dotb[0];
        }
    } else {
        #pragma unroll
        for (int nt = 0; nt < 10; ++nt) {
            int col = nt * 16 + l15;
            float bv_ = (G.bias != nullptr && col < HID) ? G.bias[col] : 0.f;
            #pragma unroll
            for (int r = 0; r < 4; ++r) {
                int row = rbase + r;
                float v = acc[nt][r] + bv_;
                if (G.relu) v = fmaxf(v, 0.f);
                G.outh[(size_t)row * G.ldo + col] = f2bf(v);
            }
        }
    }
}

// ---------------------------------------------------------------------------
// span_fused: span layer-1 + span layer-2 + layer-3 dot (unchanged this round).
// ---------------------------------------------------------------------------
__device__ __forceinline__ void add_bf8(f32x4& A, f32x4& B, u32x4 u) {
    A.x += bf2f(u.x & 0xffff); A.y += bf2f(u.x >> 16);
    A.z += bf2f(u.y & 0xffff); A.w += bf2f(u.y >> 16);
    B.x += bf2f(u.z & 0xffff); B.y += bf2f(u.z >> 16);
    B.z += bf2f(u.w & 0xffff); B.w += bf2f(u.w >> 16);
}
__device__ __forceinline__ void fma_bf8(f32x4& A, f32x4& B, u32x4 u, float w) {
    A.x = fmaf(w, bf2f(u.x & 0xffff), A.x); A.y = fmaf(w, bf2f(u.x >> 16), A.y);
    A.z = fmaf(w, bf2f(u.y & 0xffff), A.z); A.w = fmaf(w, bf2f(u.y >> 16), A.w);
    B.x = fmaf(w, bf2f(u.z & 0xffff), B.x); B.y = fmaf(w, bf2f(u.z >> 16), B.y);
    B.z = fmaf(w, bf2f(u.w & 0xffff), B.z); B.w = fmaf(w, bf2f(u.w >> 16), B.w);
}

__global__ __launch_bounds__(256) void span_fused_kernel(
        const float* __restrict__ attns,
        const int* __restrict__ starts,
        const int* __restrict__ lens,
        const unsigned short* __restrict__ Ps,
        const unsigned short* __restrict__ Pe,
        const unsigned short* __restrict__ Pm,
        const float* __restrict__ PW,           // [9][160], +bs1, zero-padded
        const unsigned short* __restrict__ W2,  // Ws2t [160][192]
        const float* __restrict__ bs2,
        const float* __restrict__ Ws3,
        const float* __restrict__ bs3,
        float* __restrict__ out) {
    constexpr int LDH = 200;                    // 400 B row stride
    __shared__ unsigned short tileAll[4][16 * LDH];
    const int wid = threadIdx.x >> 6;
    const int lane = threadIdx.x & 63;
    const int r = lane & 15;
    const int q = lane >> 4;
    unsigned short* tile = &tileAll[wid][0];
    const int s = blockIdx.x * 64 + wid * 16 + r;

    const int start = starts[s];
    const int len = lens[s];
    const int end = start + len;
    const int width = len + 1;
    const int bucket = (width >= 1) + (width >= 2) + (width >= 3) + (width >= 4) +
                       (width >= 8) + (width >= 16) + (width >= 32) + (width >= 64);

    // serial in-lane softmax (redundant across the 4 q-copies: free)
    int il[10];
    float wgt[10];
    float m = -INFINITY;
    #pragma unroll
    for (int l = 0; l < 10; ++l) {
        int iv = min(start + l, T_TOK - 1);
        il[l] = iv * 160;
        wgt[l] = (l <= len) ? attns[iv] : -INFINITY;
        m = fmaxf(m, wgt[l]);
    }
    float ssum = 0.f;
    #pragma unroll
    for (int l = 0; l < 10; ++l) { wgt[l] = __expf(wgt[l] - m); ssum += wgt[l]; }
    const float inv = 1.f / ssum;
    #pragma unroll
    for (int l = 0; l < 10; ++l) wgt[l] *= inv;

    const unsigned short* ps = Ps + (size_t)start * 160;
    const unsigned short* pe = Pe + (size_t)end * 160;
    const float* pw = PW + bucket * 160;

    // lane (r,q) accumulates chunks c = q+4i of span r's h1 row (16B each).
    #pragma unroll
    for (int i = 0; i < 5; ++i) {
        const int j0 = (q + 4 * i) * 8;
        f32x4 a0 = *(const f32x4*)(pw + j0);
        f32x4 a1 = *(const f32x4*)(pw + j0 + 4);
        add_bf8(a0, a1, *(const u32x4*)(ps + j0));
        add_bf8(a0, a1, *(const u32x4*)(pe + j0));
        #pragma unroll
        for (int l = 0; l < 10; ++l)
            fma_bf8(a0, a1, *(const u32x4*)(Pm + il[l] + j0), wgt[l]);
        u32x4 pk;
        pk.x = (unsigned)f2bf(fmaxf(a0.x, 0.f)) | ((unsigned)f2bf(fmaxf(a0.y, 0.f)) << 16);
        pk.y = (unsigned)f2bf(fmaxf(a0.z, 0.f)) | ((unsigned)f2bf(fmaxf(a0.w, 0.f)) << 16);
        pk.z = (unsigned)f2bf(fmaxf(a1.x, 0.f)) | ((unsigned)f2bf(fmaxf(a1.y, 0.f)) << 16);
        pk.w = (unsigned)f2bf(fmaxf(a1.z, 0.f)) | ((unsigned)f2bf(fmaxf(a1.w, 0.f)) << 16);
        *(u32x4*)&tile[r * LDH + j0] = pk;
    }

    // ---- phase 2: 16x160 GEMM, K=160. same-wave LDS RAW; no barrier. ----
    f32x4 acc[10];
    #pragma unroll
    for (int nt = 0; nt < 10; ++nt) acc[nt] = (f32x4){0.f, 0.f, 0.f, 0.f};
    #pragma unroll
    for (int kc = 0; kc < 5; ++kc) {
        short8 av = *(const short8*)&tile[r * LDH + kc * 32 + q * 8];
        #pragma unroll
        for (int nt = 0; nt < 10; ++nt) {
            short8 bv = *(const short8*)(W2 + (size_t)(nt * 16 + r) * 192 + kc * 32 + q * 8);
            acc[nt] = __builtin_amdgcn_mfma_f32_16x16x32_bf16(av, bv, acc[nt], 0, 0, 0);
        }
    }

    float part[4] = {0.f, 0.f, 0.f, 0.f};
    #pragma unroll
    for (int nt = 0; nt < 10; ++nt) {
        int col = nt * 16 + r;
        float b2 = (col < HID) ? bs2[col] : 0.f;
        float vv = (col < HID) ? Ws3[col] : 0.f;
        #pragma unroll
        for (int rr = 0; rr < 4; ++rr)
            part[rr] += fmaxf(acc[nt][rr] + b2, 0.f) * vv;
    }
    const int rbase = blockIdx.x * 64 + wid * 16 + q * 4;
    #pragma unroll
    for (int rr = 0; rr < 4; ++rr) {
        float p = part[rr];
        #pragma unroll
        for (int off = 1; off < 16; off <<= 1) p += __shfl_xor(p, off);
        if (r == 0) out[rbase + rr] = p + bs3[0];
    }
}

extern "C" void kernel_launch(void* const* d_in, const int* in_sizes, int n_in,
                              void* d_out, int out_size, void* d_ws, size_t ws_size,
                              hipStream_t stream) {
    const float* states = (const float*)d_in[0];
    const float* embeds = (const float*)d_in[1];
    const int* span_starts = (const int*)d_in[2];
    const int* span_lengths = (const int*)d_in[3];
    const float* Wa1 = (const float*)d_in[4];
    const float* ba1 = (const float*)d_in[5];
    const float* Wa2 = (const float*)d_in[6];
    const float* ba2 = (const float*)d_in[7];
    const float* Wa3 = (const float*)d_in[8];
    const float* ba3 = (const float*)d_in[9];
    const float* width_table = (const float*)d_in[10];
    const float* Ws1 = (const float*)d_in[11];
    const float* bs1 = (const float*)d_in[12];
    const float* Ws2 = (const float*)d_in[13];
    const float* bs2 = (const float*)d_in[14];
    const float* Ws3 = (const float*)d_in[15];
    const float* bs3 = (const float*)d_in[16];
    float* out = (float*)d_out;

    // ---- workspace layout ----
    char* w = (char*)d_ws;
    unsigned short* WtA  = (unsigned short*)w;  w += 480 * 1024 * 2;
    unsigned short* WtE  = (unsigned short*)w;  w += 160 * 512 * 2;
    unsigned short* Wa2t = (unsigned short*)w;  w += 160 * 192 * 2;
    unsigned short* Ws2t = (unsigned short*)w;  w += 160 * 192 * 2;
    float* PW    = (float*)w;                   w += 9 * 160 * 4;       // stride 160, +bs1
    float* attns = (float*)w;                   w += 8192 * 4;
    unsigned short* Psh = (unsigned short*)w;   w += (size_t)T_TOK * 160 * 2;   // bf16
    unsigned short* Peh = (unsigned short*)w;   w += (size_t)T_TOK * 160 * 2;   // bf16
    unsigned short* Pmh = (unsigned short*)w;   w += (size_t)T_TOK * 160 * 2;   // bf16
    // No memsets: pad cols (0xAA poison = finite bf16) multiply zeroed W rows.

    // ---- prep: weight transposes + width proj (+bs1) ----
    PrepTab pt;
    pt.g[0] = { Wa1,              WtA,              1024, 1024, (160*1024 + 255)/256 };
    pt.g[1] = { Ws1,              WtA + 160*1024,   1024, 1024, (160*1024 + 255)/256 };
    pt.g[2] = { Ws1 + 1024*150,   WtA + 320*1024,   1024, 1024, (160*1024 + 255)/256 };
    pt.g[3] = { Ws1 + 2048*150,   WtE,               512,  512, (160*512  + 255)/256 };
    pt.g[4] = { Wa2,              Wa2t,              150,  192, (160*192  + 255)/256 };
    pt.g[5] = { Ws2,              Ws2t,              150,  192, (160*192  + 255)/256 };
    pt.wt = width_table; pt.Ws1w = Ws1 + 2560*150; pt.bs1 = bs1; pt.PW = PW;
    int wblk = 0; for (int i = 0; i < 6; ++i) wblk += pt.g[i].nblk;
    prep_kernel<<<wblk + 9, 256, 0, stream>>>(pt);

    GG z = {};

    // ---- fused GEMM1+2 + attn layers 2/3: 4 groups, 512 blocks ----
    GTab t1; t1.ng = 4;
    t1.g[0] = z; t1.g[0].A = states; t1.g[0].lda = 1024; t1.g[0].W = WtA;            t1.g[0].K = 1024;
    t1.g[0].nrb = 128; t1.g[0].bias = ba1;
    t1.g[0].W2 = Wa2t; t1.g[0].bias2 = ba2;
    t1.g[0].dotv = Wa3; t1.g[0].dotb = ba3; t1.g[0].dotout = attns;
    t1.g[1] = z; t1.g[1].A = states; t1.g[1].lda = 1024; t1.g[1].W = WtA + 160*1024; t1.g[1].K = 1024;
    t1.g[1].nrb = 128; t1.g[1].outh = Psh; t1.g[1].ldo = 160;
    t1.g[2] = z; t1.g[2].A = states; t1.g[2].lda = 1024; t1.g[2].W = WtA + 320*1024; t1.g[2].K = 1024;
    t1.g[2].nrb = 128; t1.g[2].outh = Peh; t1.g[2].ldo = 160;
    t1.g[3] = z; t1.g[3].A = embeds; t1.g[3].lda = 512;  t1.g[3].W = WtE;            t1.g[3].K = 512;
    t1.g[3].nrb = 128; t1.g[3].outh = Pmh; t1.g[3].ldo = 160;
    gemm_fused<1, true><<<512, 256, 0, stream>>>(t1);

    // ---- fused span layer1 + layer2 + layer3 dot -> out ----
    span_fused_kernel<<<S_SPAN / 64, 256, 0, stream>>>(attns, span_starts, span_lengths,
                                                       Psh, Peh, Pmh, PW, Ws2t,
                                                       bs2, Ws3, bs3, out);
}

// Round 3
// 176.981 us; speedup vs baseline: 1.2570x; 1.2570x over previous
//
#include <hip/hip_runtime.h>
#include <math.h>

#define T_TOK 8192
#define A_DIM 1024
#define E_DIM 512
#define S_SPAN 32768
#define HID 150

typedef __attribute__((ext_vector_type(8))) short short8;
typedef __attribute__((ext_vector_type(4))) float f32x4;
typedef __attribute__((ext_vector_type(4))) unsigned int u32x4;

__device__ __forceinline__ unsigned short f2bf(float f) {
    unsigned int u = __builtin_bit_cast(unsigned int, f);
    u += 0x7FFFu + ((u >> 16) & 1u);          // RNE
    return (unsigned short)(u >> 16);
}
__device__ __forceinline__ float bf2f(unsigned int h16) {
    unsigned int u = h16 << 16;
    return __builtin_bit_cast(float, u);
}
__device__ __forceinline__ short8 cast8(f32x4 a, f32x4 b) {
    short8 r;
    r[0] = (short)f2bf(a.x); r[1] = (short)f2bf(a.y);
    r[2] = (short)f2bf(a.z); r[3] = (short)f2bf(a.w);
    r[4] = (short)f2bf(b.x); r[5] = (short)f2bf(b.y);
    r[6] = (short)f2bf(b.z); r[7] = (short)f2bf(b.w);
    return r;
}

// ---------------------------------------------------------------------------
// prep: 6 weight transposes + width projection (+bs1 folded, zero-padded 160)
// ---------------------------------------------------------------------------
struct WConv { const float* src; unsigned short* dst; int K0; int Kpad; int nblk; };
struct PrepTab {
    WConv g[6];
    const float* wt; const float* Ws1w; const float* bs1; float* PW;
};

__global__ __launch_bounds__(256) void prep_kernel(PrepTab tab) {
    int b = blockIdx.x;
    #pragma unroll
    for (int gi = 0; gi < 6; ++gi) {
        if (b < tab.g[gi].nblk) {
            int idx = b * 256 + threadIdx.x;               // idx = k*160 + j
            int Kpad = tab.g[gi].Kpad;
            if (idx < Kpad * 160) {
                int k = idx / 160, j = idx - k * 160;
                float v = (j < HID && k < tab.g[gi].K0)
                          ? tab.g[gi].src[(size_t)k * HID + j] : 0.f;   // coalesced read
                tab.g[gi].dst[(size_t)j * Kpad + k] = f2bf(v);          // scattered write
            }
            return;
        }
        b -= tab.g[gi].nblk;
    }
    // width projection: 9 blocks. PW row = width_table[b] @ Ws1w + bs1,
    // stride 160 with exact zeros at j>=150 (GEMM K-pad for span_fused).
    int j = threadIdx.x;
    if (j < 160) {
        float acc = 0.f;
        if (j < HID) {
            for (int k = 0; k < 20; ++k)
                acc = fmaf(tab.wt[b * 20 + k], tab.Ws1w[k * HID + j], acc);
            acc += tab.bs1[j];
        }
        tab.PW[b * 160 + j] = acc;
    }
}

// ---------------------------------------------------------------------------
// unified MFMA GEMM, 2-deep pipelined K-loop, STATIC register sets.
// Round-2's runtime-indexed stg[pb][i] spilled the whole pipeline state to
// scratch (WRITE_SIZE 8->132 MB, VGPR stuck at 84 — rule #20). Fix: manual
// 2x chunk unroll with NAMED sets (wA/wB, fAa/fAb, hAa/hAb); every index is
// a compile-time literal. Requires nch even (K=1024 -> 16, K=512 -> 8).
// Schedule per pair (c even):
//   even phase: issue loads c+2 -> A-set; ds_write c+1 (B-set, loaded a full
//               chunk ago -> vmcnt satisfied); MFMA c from LDS[0]; barrier.
//   odd phase:  issue loads c+3 -> B-set; ds_write c+2 (A-set); MFMA c+1
//               from LDS[1]; barrier.
// Bit-identical accumulation order vs the 1-deep loop.
// W2 path — fused attn layer2+3 in group-0 epilogue (unchanged).
// ---------------------------------------------------------------------------
struct GG {
    const void* A; int lda;
    const unsigned short* W; int K; int nrb;
    unsigned short* outh; int ldo;
    const float* bias; int relu;
    const float* dotv; const float* dotb; float* dotout;
    const unsigned short* W2; const float* bias2;
};
struct GTab { GG g[4]; int ng; };

template <int TAG, bool AF32>
__global__ __launch_bounds__(256) void gemm_fused(GTab tab) {
    constexpr int LDW = 72;
    __shared__ unsigned short WtL[2][160 * LDW];

    int b = blockIdx.x;
    int gi = 0;
    while (gi < tab.ng - 1 && b >= tab.g[gi].nrb) { b -= tab.g[gi].nrb; ++gi; }
    const GG G = tab.g[gi];

    const int tid = threadIdx.x;
    const int wid = tid >> 6;
    const int lane = tid & 63;
    const int l15 = lane & 15;
    const int quad = lane >> 4;
    const int row0 = b * 64 + wid * 16 + l15;
    const int K = G.K;
    const int nch = K >> 6;                       // even: 16 (K=1024) or 8 (K=512)
    const float* Af = (const float*)G.A + (size_t)row0 * G.lda;
    const unsigned short* Ah = (const unsigned short*)G.A + (size_t)row0 * G.lda;

    int sn[5], sk[5];
    #pragma unroll
    for (int i = 0; i < 5; ++i) { int u = tid + i * 256; sn[i] = u >> 3; sk[i] = (u & 7) * 8; }

    f32x4 acc[10];
    #pragma unroll
    for (int nt = 0; nt < 10; ++nt) acc[nt] = (f32x4){0.f, 0.f, 0.f, 0.f};

    // named 2-deep register sets — ALL statically indexed
    u32x4 wA[5], wB[5];
    f32x4 fAa[4], fAb[4];
    short8 hAa[2], hAb[2];
    short8 avc0, avc1;

#define LOAD_W(SET, KOFF)                                                     \
    {   _Pragma("unroll")                                                     \
        for (int i = 0; i < 5; ++i)                                           \
            SET[i] = *(const u32x4*)(G.W + (size_t)sn[i] * K + (KOFF) + sk[i]); }
#define LOAD_A(FSET, HSET, KOFF)                                              \
    if (AF32) {                                                               \
        FSET[0] = *(const f32x4*)(Af + (KOFF) + quad * 8);                    \
        FSET[1] = *(const f32x4*)(Af + (KOFF) + quad * 8 + 4);                \
        FSET[2] = *(const f32x4*)(Af + (KOFF) + 32 + quad * 8);               \
        FSET[3] = *(const f32x4*)(Af + (KOFF) + 32 + quad * 8 + 4);           \
    } else {                                                                  \
        HSET[0] = *(const short8*)(Ah + (KOFF) + quad * 8);                   \
        HSET[1] = *(const short8*)(Ah + (KOFF) + 32 + quad * 8);              \
    }
#define STORE_W(SET, BUF)                                                     \
    {   _Pragma("unroll")                                                     \
        for (int i = 0; i < 5; ++i)                                           \
            *(u32x4*)&WtL[BUF][sn[i] * LDW + sk[i]] = SET[i]; }
#define SET_AVC(FSET, HSET)                                                   \
    if (AF32) { avc0 = cast8(FSET[0], FSET[1]); avc1 = cast8(FSET[2], FSET[3]); } \
    else      { avc0 = HSET[0]; avc1 = HSET[1]; }
#define MFMA_BLOCK(BUF)                                                       \
    {   _Pragma("unroll")                                                     \
        for (int nt = 0; nt < 10; ++nt) {                                     \
            short8 bv0 = *(const short8*)&WtL[BUF][(nt * 16 + l15) * LDW + quad * 8]; \
            acc[nt] = __builtin_amdgcn_mfma_f32_16x16x32_bf16(avc0, bv0, acc[nt], 0, 0, 0); \
            short8 bv1 = *(const short8*)&WtL[BUF][(nt * 16 + l15) * LDW + 32 + quad * 8]; \
            acc[nt] = __builtin_amdgcn_mfma_f32_16x16x32_bf16(avc1, bv1, acc[nt], 0, 0, 0); \
        } }

    // ---- prologue: issue chunk 0 AND chunk 1 loads before any wait ----
    LOAD_W(wA, 0);
    LOAD_A(fAa, hAa, 0);
    LOAD_W(wB, 64);
    LOAD_A(fAb, hAb, 64);
    // stage chunk 0 (one-time vmcnt stall; chunk-1 loads stay in flight)
    STORE_W(wA, 0);
    SET_AVC(fAa, hAa);
    __syncthreads();

    for (int c = 0; c < nch; c += 2) {
        // ---- even chunk c (LDS buf 0) ----
        const bool mA = (c + 2 < nch);
        if (mA) {
            const int kn = (c + 2) << 6;
            LOAD_W(wA, kn);
            LOAD_A(fAa, hAa, kn);
        }
        STORE_W(wB, 1);                     // chunk c+1: loaded a full chunk ago
        MFMA_BLOCK(0);                      // chunk c
        SET_AVC(fAb, hAb);                  // A operand for chunk c+1
        __syncthreads();

        // ---- odd chunk c+1 (LDS buf 1) ----
        const bool mB = (c + 3 < nch);
        if (mB) {
            const int kn = (c + 3) << 6;
            LOAD_W(wB, kn);
            LOAD_A(fAb, hAb, kn);
        }
        if (mA) STORE_W(wA, 0);             // chunk c+2
        MFMA_BLOCK(1);                      // chunk c+1
        if (mA) SET_AVC(fAa, hAa);          // A operand for chunk c+2
        __syncthreads();
    }

#undef LOAD_W
#undef LOAD_A
#undef STORE_W
#undef SET_AVC
#undef MFMA_BLOCK

    const int rbase = b * 64 + wid * 16 + quad * 4;
    if (G.W2) {
        // ---- fused attn layer2+3 ----
        constexpr int LDH = 168;
        unsigned short* tile = &WtL[0][0] + wid * 16 * LDH;   // per-wave region
        #pragma unroll
        for (int nt = 0; nt < 10; ++nt) {
            int col = nt * 16 + l15;
            float bv_ = (col < HID) ? G.bias[col] : 0.f;
            #pragma unroll
            for (int r = 0; r < 4; ++r) {
                float v = fmaxf(acc[nt][r] + bv_, 0.f);
                tile[(quad * 4 + r) * LDH + col] = f2bf(v);
            }
        }
        // same-wave RAW through LDS: compiler inserts lgkmcnt; no barrier.
        f32x4 acc2[10];
        #pragma unroll
        for (int nt = 0; nt < 10; ++nt) acc2[nt] = (f32x4){0.f, 0.f, 0.f, 0.f};
        #pragma unroll
        for (int kc = 0; kc < 5; ++kc) {
            short8 av = *(const short8*)&tile[l15 * LDH + kc * 32 + quad * 8];
            #pragma unroll
            for (int nt = 0; nt < 10; ++nt) {
                short8 bv = *(const short8*)(G.W2 + (size_t)(nt * 16 + l15) * 192 + kc * 32 + quad * 8);
                acc2[nt] = __builtin_amdgcn_mfma_f32_16x16x32_bf16(av, bv, acc2[nt], 0, 0, 0);
            }
        }
        float part[4] = {0.f, 0.f, 0.f, 0.f};
        #pragma unroll
        for (int nt = 0; nt < 10; ++nt) {
            int col = nt * 16 + l15;
            float b2 = (col < HID) ? G.bias2[col] : 0.f;
            float vv = (col < HID) ? G.dotv[col] : 0.f;
            #pragma unroll
            for (int r = 0; r < 4; ++r)
                part[r] += fmaxf(acc2[nt][r] + b2, 0.f) * vv;
        }
        #pragma unroll
        for (int r = 0; r < 4; ++r) {
            float p = part[r];
            #pragma unroll
            for (int off = 1; off < 16; off <<= 1) p += __shfl_xor(p, off);
            if (l15 == 0) G.dotout[rbase + r] = p + G.dotb[0];
        }
    } else if (G.dotout) {
        float part[4] = {0.f, 0.f, 0.f, 0.f};
        #pragma unroll
        for (int nt = 0; nt < 10; ++nt) {
            int col = nt * 16 + l15;
            float bv_ = (col < HID) ? G.bias[col] : 0.f;
            float vv = (col < HID) ? G.dotv[col] : 0.f;
            #pragma unroll
            for (int r = 0; r < 4; ++r)
                part[r] += fmaxf(acc[nt][r] + bv_, 0.f) * vv;
        }
        #pragma unroll
        for (int r = 0; r < 4; ++r) {
            float p = part[r];
            #pragma unroll
            for (int off = 1; off < 16; off <<= 1) p += __shfl_xor(p, off);
            if (l15 == 0) G.dotout[rbase + r] = p + G.dotb[0];
        }
    } else {
        #pragma unroll
        for (int nt = 0; nt < 10; ++nt) {
            int col = nt * 16 + l15;
            float bv_ = (G.bias != nullptr && col < HID) ? G.bias[col] : 0.f;
            #pragma unroll
            for (int r = 0; r < 4; ++r) {
                int row = rbase + r;
                float v = acc[nt][r] + bv_;
                if (G.relu) v = fmaxf(v, 0.f);
                G.outh[(size_t)row * G.ldo + col] = f2bf(v);
            }
        }
    }
}

// ---------------------------------------------------------------------------
// span_fused: span layer-1 + span layer-2 + layer-3 dot (unchanged).
// ---------------------------------------------------------------------------
__device__ __forceinline__ void add_bf8(f32x4& A, f32x4& B, u32x4 u) {
    A.x += bf2f(u.x & 0xffff); A.y += bf2f(u.x >> 16);
    A.z += bf2f(u.y & 0xffff); A.w += bf2f(u.y >> 16);
    B.x += bf2f(u.z & 0xffff); B.y += bf2f(u.z >> 16);
    B.z += bf2f(u.w & 0xffff); B.w += bf2f(u.w >> 16);
}
__device__ __forceinline__ void fma_bf8(f32x4& A, f32x4& B, u32x4 u, float w) {
    A.x = fmaf(w, bf2f(u.x & 0xffff), A.x); A.y = fmaf(w, bf2f(u.x >> 16), A.y);
    A.z = fmaf(w, bf2f(u.y & 0xffff), A.z); A.w = fmaf(w, bf2f(u.y >> 16), A.w);
    B.x = fmaf(w, bf2f(u.z & 0xffff), B.x); B.y = fmaf(w, bf2f(u.z >> 16), B.y);
    B.z = fmaf(w, bf2f(u.w & 0xffff), B.z); B.w = fmaf(w, bf2f(u.w >> 16), B.w);
}

__global__ __launch_bounds__(256) void span_fused_kernel(
        const float* __restrict__ attns,
        const int* __restrict__ starts,
        const int* __restrict__ lens,
        const unsigned short* __restrict__ Ps,
        const unsigned short* __restrict__ Pe,
        const unsigned short* __restrict__ Pm,
        const float* __restrict__ PW,           // [9][160], +bs1, zero-padded
        const unsigned short* __restrict__ W2,  // Ws2t [160][192]
        const float* __restrict__ bs2,
        const float* __restrict__ Ws3,
        const float* __restrict__ bs3,
        float* __restrict__ out) {
    constexpr int LDH = 200;                    // 400 B row stride
    __shared__ unsigned short tileAll[4][16 * LDH];
    const int wid = threadIdx.x >> 6;
    const int lane = threadIdx.x & 63;
    const int r = lane & 15;
    const int q = lane >> 4;
    unsigned short* tile = &tileAll[wid][0];
    const int s = blockIdx.x * 64 + wid * 16 + r;

    const int start = starts[s];
    const int len = lens[s];
    const int end = start + len;
    const int width = len + 1;
    const int bucket = (width >= 1) + (width >= 2) + (width >= 3) + (width >= 4) +
                       (width >= 8) + (width >= 16) + (width >= 32) + (width >= 64);

    // serial in-lane softmax (redundant across the 4 q-copies: free)
    int il[10];
    float wgt[10];
    float m = -INFINITY;
    #pragma unroll
    for (int l = 0; l < 10; ++l) {
        int iv = min(start + l, T_TOK - 1);
        il[l] = iv * 160;
        wgt[l] = (l <= len) ? attns[iv] : -INFINITY;
        m = fmaxf(m, wgt[l]);
    }
    float ssum = 0.f;
    #pragma unroll
    for (int l = 0; l < 10; ++l) { wgt[l] = __expf(wgt[l] - m); ssum += wgt[l]; }
    const float inv = 1.f / ssum;
    #pragma unroll
    for (int l = 0; l < 10; ++l) wgt[l] *= inv;

    const unsigned short* ps = Ps + (size_t)start * 160;
    const unsigned short* pe = Pe + (size_t)end * 160;
    const float* pw = PW + bucket * 160;

    // lane (r,q) accumulates chunks c = q+4i of span r's h1 row (16B each).
    #pragma unroll
    for (int i = 0; i < 5; ++i) {
        const int j0 = (q + 4 * i) * 8;
        f32x4 a0 = *(const f32x4*)(pw + j0);
        f32x4 a1 = *(const f32x4*)(pw + j0 + 4);
        add_bf8(a0, a1, *(const u32x4*)(ps + j0));
        add_bf8(a0, a1, *(const u32x4*)(pe + j0));
        #pragma unroll
        for (int l = 0; l < 10; ++l)
            fma_bf8(a0, a1, *(const u32x4*)(Pm + il[l] + j0), wgt[l]);
        u32x4 pk;
        pk.x = (unsigned)f2bf(fmaxf(a0.x, 0.f)) | ((unsigned)f2bf(fmaxf(a0.y, 0.f)) << 16);
        pk.y = (unsigned)f2bf(fmaxf(a0.z, 0.f)) | ((unsigned)f2bf(fmaxf(a0.w, 0.f)) << 16);
        pk.z = (unsigned)f2bf(fmaxf(a1.x, 0.f)) | ((unsigned)f2bf(fmaxf(a1.y, 0.f)) << 16);
        pk.w = (unsigned)f2bf(fmaxf(a1.z, 0.f)) | ((unsigned)f2bf(fmaxf(a1.w, 0.f)) << 16);
        *(u32x4*)&tile[r * LDH + j0] = pk;
    }

    // ---- phase 2: 16x160 GEMM, K=160. same-wave LDS RAW; no barrier. ----
    f32x4 acc[10];
    #pragma unroll
    for (int nt = 0; nt < 10; ++nt) acc[nt] = (f32x4){0.f, 0.f, 0.f, 0.f};
    #pragma unroll
    for (int kc = 0; kc < 5; ++kc) {
        short8 av = *(const short8*)&tile[r * LDH + kc * 32 + q * 8];
        #pragma unroll
        for (int nt = 0; nt < 10; ++nt) {
            short8 bv = *(const short8*)(W2 + (size_t)(nt * 16 + r) * 192 + kc * 32 + q * 8);
            acc[nt] = __builtin_amdgcn_mfma_f32_16x16x32_bf16(av, bv, acc[nt], 0, 0, 0);
        }
    }

    float part[4] = {0.f, 0.f, 0.f, 0.f};
    #pragma unroll
    for (int nt = 0; nt < 10; ++nt) {
        int col = nt * 16 + r;
        float b2 = (col < HID) ? bs2[col] : 0.f;
        float vv = (col < HID) ? Ws3[col] : 0.f;
        #pragma unroll
        for (int rr = 0; rr < 4; ++rr)
            part[rr] += fmaxf(acc[nt][rr] + b2, 0.f) * vv;
    }
    const int rbase = blockIdx.x * 64 + wid * 16 + q * 4;
    #pragma unroll
    for (int rr = 0; rr < 4; ++rr) {
        float p = part[rr];
        #pragma unroll
        for (int off = 1; off < 16; off <<= 1) p += __shfl_xor(p, off);
        if (r == 0) out[rbase + rr] = p + bs3[0];
    }
}

extern "C" void kernel_launch(void* const* d_in, const int* in_sizes, int n_in,
                              void* d_out, int out_size, void* d_ws, size_t ws_size,
                              hipStream_t stream) {
    const float* states = (const float*)d_in[0];
    const float* embeds = (const float*)d_in[1];
    const int* span_starts = (const int*)d_in[2];
    const int* span_lengths = (const int*)d_in[3];
    const float* Wa1 = (const float*)d_in[4];
    const float* ba1 = (const float*)d_in[5];
    const float* Wa2 = (const float*)d_in[6];
    const float* ba2 = (const float*)d_in[7];
    const float* Wa3 = (const float*)d_in[8];
    const float* ba3 = (const float*)d_in[9];
    const float* width_table = (const float*)d_in[10];
    const float* Ws1 = (const float*)d_in[11];
    const float* bs1 = (const float*)d_in[12];
    const float* Ws2 = (const float*)d_in[13];
    const float* bs2 = (const float*)d_in[14];
    const float* Ws3 = (const float*)d_in[15];
    const float* bs3 = (const float*)d_in[16];
    float* out = (float*)d_out;

    // ---- workspace layout ----
    char* w = (char*)d_ws;
    unsigned short* WtA  = (unsigned short*)w;  w += 480 * 1024 * 2;
    unsigned short* WtE  = (unsigned short*)w;  w += 160 * 512 * 2;
    unsigned short* Wa2t = (unsigned short*)w;  w += 160 * 192 * 2;
    unsigned short* Ws2t = (unsigned short*)w;  w += 160 * 192 * 2;
    float* PW    = (float*)w;                   w += 9 * 160 * 4;       // stride 160, +bs1
    float* attns = (float*)w;                   w += 8192 * 4;
    unsigned short* Psh = (unsigned short*)w;   w += (size_t)T_TOK * 160 * 2;   // bf16
    unsigned short* Peh = (unsigned short*)w;   w += (size_t)T_TOK * 160 * 2;   // bf16
    unsigned short* Pmh = (unsigned short*)w;   w += (size_t)T_TOK * 160 * 2;   // bf16
    // No memsets: pad cols (0xAA poison = finite bf16) multiply zeroed W rows.

    // ---- prep: weight transposes + width proj (+bs1) ----
    PrepTab pt;
    pt.g[0] = { Wa1,              WtA,              1024, 1024, (160*1024 + 255)/256 };
    pt.g[1] = { Ws1,              WtA + 160*1024,   1024, 1024, (160*1024 + 255)/256 };
    pt.g[2] = { Ws1 + 1024*150,   WtA + 320*1024,   1024, 1024, (160*1024 + 255)/256 };
    pt.g[3] = { Ws1 + 2048*150,   WtE,               512,  512, (160*512  + 255)/256 };
    pt.g[4] = { Wa2,              Wa2t,              150,  192, (160*192  + 255)/256 };
    pt.g[5] = { Ws2,              Ws2t,              150,  192, (160*192  + 255)/256 };
    pt.wt = width_table; pt.Ws1w = Ws1 + 2560*150; pt.bs1 = bs1; pt.PW = PW;
    int wblk = 0; for (int i = 0; i < 6; ++i) wblk += pt.g[i].nblk;
    prep_kernel<<<wblk + 9, 256, 0, stream>>>(pt);

    GG z = {};

    // ---- fused GEMM1+2 + attn layers 2/3: 4 groups, 512 blocks ----
    GTab t1; t1.ng = 4;
    t1.g[0] = z; t1.g[0].A = states; t1.g[0].lda = 1024; t1.g[0].W = WtA;            t1.g[0].K = 1024;
    t1.g[0].nrb = 128; t1.g[0].bias = ba1;
    t1.g[0].W2 = Wa2t; t1.g[0].bias2 = ba2;
    t1.g[0].dotv = Wa3; t1.g[0].dotb = ba3; t1.g[0].dotout = attns;
    t1.g[1] = z; t1.g[1].A = states; t1.g[1].lda = 1024; t1.g[1].W = WtA + 160*1024; t1.g[1].K = 1024;
    t1.g[1].nrb = 128; t1.g[1].outh = Psh; t1.g[1].ldo = 160;
    t1.g[2] = z; t1.g[2].A = states; t1.g[2].lda = 1024; t1.g[2].W = WtA + 320*1024; t1.g[2].K = 1024;
    t1.g[2].nrb = 128; t1.g[2].outh = Peh; t1.g[2].ldo = 160;
    t1.g[3] = z; t1.g[3].A = embeds; t1.g[3].lda = 512;  t1.g[3].W = WtE;            t1.g[3].K = 512;
    t1.g[3].nrb = 128; t1.g[3].outh = Pmh; t1.g[3].ldo = 160;
    gemm_fused<1, true><<<512, 256, 0, stream>>>(t1);

    // ---- fused span layer1 + layer2 + layer3 dot -> out ----
    span_fused_kernel<<<S_SPAN / 64, 256, 0, stream>>>(attns, span_starts, span_lengths,
                                                       Psh, Peh, Pmh, PW, Ws2t,
                                                       bs2, Ws3, bs3, out);
}

// Round 5
// 172.932 us; speedup vs baseline: 1.2864x; 1.0234x over previous
//
#include <hip/hip_runtime.h>
#include <math.h>

#define T_TOK 8192
#define A_DIM 1024
#define E_DIM 512
#define S_SPAN 32768
#define HID 150

typedef __attribute__((ext_vector_type(8))) short short8;
typedef __attribute__((ext_vector_type(4))) float f32x4;
typedef __attribute__((ext_vector_type(4))) unsigned int u32x4;

__device__ __forceinline__ unsigned short f2bf(float f) {
    unsigned int u = __builtin_bit_cast(unsigned int, f);
    u += 0x7FFFu + ((u >> 16) & 1u);          // RNE
    return (unsigned short)(u >> 16);
}
__device__ __forceinline__ float bf2f(unsigned int h16) {
    unsigned int u = h16 << 16;
    return __builtin_bit_cast(float, u);
}
__device__ __forceinline__ short8 cast8(f32x4 a, f32x4 b) {
    short8 r;
    r[0] = (short)f2bf(a.x); r[1] = (short)f2bf(a.y);
    r[2] = (short)f2bf(a.z); r[3] = (short)f2bf(a.w);
    r[4] = (short)f2bf(b.x); r[5] = (short)f2bf(b.y);
    r[6] = (short)f2bf(b.z); r[7] = (short)f2bf(b.w);
    return r;
}

// Publish-barrier: ds ops retired (lgkmcnt 0) but VMEM loads stay IN FLIGHT
// across the barrier (no vmcnt drain — unlike __syncthreads). sched_barrier
// pins ordering so no LDS op migrates across. Hazard audit (1 barrier/chunk):
// my ds_writes (publish) and ds_reads (WAR vs next chunk's writers) are both
// lgkm-retired before I arrive; other waves' likewise. m201-verified pattern.
__device__ __forceinline__ void pub_barrier() {
    __builtin_amdgcn_sched_barrier(0);
    asm volatile("s_waitcnt lgkmcnt(0)" ::: "memory");
    __builtin_amdgcn_sched_barrier(0);
    __builtin_amdgcn_s_barrier();
    __builtin_amdgcn_sched_barrier(0);
}

// ---------------------------------------------------------------------------
// prep: weight transposes via LDS 64x64 tiles (coalesced BOTH sides; the old
// version did ~1M scattered 2-byte global stores = 1 cache line per 4 useful
// bytes) + width projection (+bs1 folded, zero-padded 160).
// Bit-identical output: same f2bf values, same placement, same zero pads.
// ---------------------------------------------------------------------------
struct WConv { const float* src; unsigned short* dst; int K0; int Kpad; int nblk; };
struct PrepTab {
    WConv g[6];
    const float* wt; const float* Ws1w; const float* bs1; float* PW;
};

__global__ __launch_bounds__(256) void prep_kernel(PrepTab tab) {
    __shared__ float tl[64][65];                 // stride 65: conflict-free transpose
    int b = blockIdx.x;
    #pragma unroll
    for (int gi = 0; gi < 6; ++gi) {
        if (b < tab.g[gi].nblk) {
            const int kt   = tab.g[gi].Kpad >> 6;        // k-tiles
            const int j0   = (b / kt) * 64;              // output-row tile base
            const int k0   = (b % kt) * 64;              // k tile base
            const int K0   = tab.g[gi].K0;
            const int Kpad = tab.g[gi].Kpad;
            const int ty = threadIdx.x >> 6, tx = threadIdx.x & 63;
            const float* src = tab.g[gi].src;
            #pragma unroll
            for (int r = 0; r < 16; ++r) {               // coalesced src reads
                int k = k0 + ty * 16 + r;
                int j = j0 + tx;
                tl[ty * 16 + r][tx] = (j < HID && k < K0)
                                      ? src[(size_t)k * HID + j] : 0.f;
            }
            __syncthreads();
            unsigned short* dst = tab.g[gi].dst;
            #pragma unroll
            for (int r = 0; r < 16; ++r) {               // coalesced dst writes
                int j = j0 + ty * 16 + r;
                if (j < 160)
                    dst[(size_t)j * Kpad + k0 + tx] = f2bf(tl[tx][ty * 16 + r]);
            }
            return;
        }
        b -= tab.g[gi].nblk;
    }
    // width projection: 9 blocks. PW row = width_table[b] @ Ws1w + bs1,
    // stride 160 with exact zeros at j>=150 (GEMM K-pad for span_fused).
    int j = threadIdx.x;
    if (j < 160) {
        float acc = 0.f;
        if (j < HID) {
            for (int k = 0; k < 20; ++k)
                acc = fmaf(tab.wt[b * 20 + k], tab.Ws1w[k * HID + j], acc);
            acc += tab.bs1[j];
        }
        tab.PW[b * 160 + j] = acc;
    }
}

// ---------------------------------------------------------------------------
// unified MFMA GEMM, 2-deep pipelined K-loop, STATIC register sets (r3), and
// counted-wait barriers (r4): pub_barrier keeps the c+2 global loads in
// flight across the chunk barrier; the compiler auto-inserts vmcnt(N) before
// the ds_write that consumes them one full chunk later. __syncthreads would
// have drained vmcnt(0) every chunk (the §5 barrier-drain stall).
// Bit-identical accumulation order vs the 1-deep loop.
// W2 path — fused attn layer2+3 in group-0 epilogue (unchanged).
// ---------------------------------------------------------------------------
struct GG {
    const void* A; int lda;
    const unsigned short* W; int K; int nrb;
    unsigned short* outh; int ldo;
    const float* bias; int relu;
    const float* dotv; const float* dotb; float* dotout;
    const unsigned short* W2; const float* bias2;
};
struct GTab { GG g[4]; int ng; };

template <int TAG, bool AF32>
__global__ __launch_bounds__(256) void gemm_fused(GTab tab) {
    constexpr int LDW = 72;
    __shared__ unsigned short WtL[2][160 * LDW];

    int b = blockIdx.x;
    int gi = 0;
    while (gi < tab.ng - 1 && b >= tab.g[gi].nrb) { b -= tab.g[gi].nrb; ++gi; }
    const GG G = tab.g[gi];

    const int tid = threadIdx.x;
    const int wid = tid >> 6;
    const int lane = tid & 63;
    const int l15 = lane & 15;
    const int quad = lane >> 4;
    const int row0 = b * 64 + wid * 16 + l15;
    const int K = G.K;
    const int nch = K >> 6;                       // even: 16 (K=1024) or 8 (K=512)
    const float* Af = (const float*)G.A + (size_t)row0 * G.lda;
    const unsigned short* Ah = (const unsigned short*)G.A + (size_t)row0 * G.lda;

    int sn[5], sk[5];
    #pragma unroll
    for (int i = 0; i < 5; ++i) { int u = tid + i * 256; sn[i] = u >> 3; sk[i] = (u & 7) * 8; }

    f32x4 acc[10];
    #pragma unroll
    for (int nt = 0; nt < 10; ++nt) acc[nt] = (f32x4){0.f, 0.f, 0.f, 0.f};

    // named 2-deep register sets — ALL statically indexed (rule #20)
    u32x4 wA[5], wB[5];
    f32x4 fAa[4], fAb[4];
    short8 hAa[2], hAb[2];
    short8 avc0, avc1;

#define LOAD_W(SET, KOFF)                                                     \
    {   _Pragma("unroll")                                                     \
        for (int i = 0; i < 5; ++i)                                           \
            SET[i] = *(const u32x4*)(G.W + (size_t)sn[i] * K + (KOFF) + sk[i]); }
#define LOAD_A(FSET, HSET, KOFF)                                              \
    if (AF32) {                                                               \
        FSET[0] = *(const f32x4*)(Af + (KOFF) + quad * 8);                    \
        FSET[1] = *(const f32x4*)(Af + (KOFF) + quad * 8 + 4);                \
        FSET[2] = *(const f32x4*)(Af + (KOFF) + 32 + quad * 8);               \
        FSET[3] = *(const f32x4*)(Af + (KOFF) + 32 + quad * 8 + 4);           \
    } else {                                                                  \
        HSET[0] = *(const short8*)(Ah + (KOFF) + quad * 8);                   \
        HSET[1] = *(const short8*)(Ah + (KOFF) + 32 + quad * 8);              \
    }
#define STORE_W(SET, BUF)                                                     \
    {   _Pragma("unroll")                                                     \
        for (int i = 0; i < 5; ++i)                                           \
            *(u32x4*)&WtL[BUF][sn[i] * LDW + sk[i]] = SET[i]; }
#define SET_AVC(FSET, HSET)                                                   \
    if (AF32) { avc0 = cast8(FSET[0], FSET[1]); avc1 = cast8(FSET[2], FSET[3]); } \
    else      { avc0 = HSET[0]; avc1 = HSET[1]; }
#define MFMA_BLOCK(BUF)                                                       \
    {   _Pragma("unroll")                                                     \
        for (int nt = 0; nt < 10; ++nt) {                                     \
            short8 bv0 = *(const short8*)&WtL[BUF][(nt * 16 + l15) * LDW + quad * 8]; \
            acc[nt] = __builtin_amdgcn_mfma_f32_16x16x32_bf16(avc0, bv0, acc[nt], 0, 0, 0); \
            short8 bv1 = *(const short8*)&WtL[BUF][(nt * 16 + l15) * LDW + 32 + quad * 8]; \
            acc[nt] = __builtin_amdgcn_mfma_f32_16x16x32_bf16(avc1, bv1, acc[nt], 0, 0, 0); \
        } }

    // ---- prologue: issue chunk 0 AND chunk 1 loads before any wait ----
    LOAD_W(wA, 0);
    LOAD_A(fAa, hAa, 0);
    LOAD_W(wB, 64);
    LOAD_A(fAb, hAb, 64);
    // stage chunk 0 (one-time vmcnt stall; chunk-1 loads stay in flight)
    STORE_W(wA, 0);
    SET_AVC(fAa, hAa);
    pub_barrier();

    for (int c = 0; c < nch; c += 2) {
        // ---- even chunk c (LDS buf 0) ----
        const bool mA = (c + 2 < nch);
        if (mA) {
            const int kn = (c + 2) << 6;
            LOAD_W(wA, kn);
            LOAD_A(fAa, hAa, kn);
        }
        STORE_W(wB, 1);                     // chunk c+1: loaded a full chunk ago
        MFMA_BLOCK(0);                      // chunk c
        SET_AVC(fAb, hAb);                  // A operand for chunk c+1
        pub_barrier();

        // ---- odd chunk c+1 (LDS buf 1) ----
        const bool mB = (c + 3 < nch);
        if (mB) {
            const int kn = (c + 3) << 6;
            LOAD_W(wB, kn);
            LOAD_A(fAb, hAb, kn);
        }
        if (mA) STORE_W(wA, 0);             // chunk c+2
        MFMA_BLOCK(1);                      // chunk c+1
        if (mA) SET_AVC(fAa, hAa);          // A operand for chunk c+2
        pub_barrier();
    }

#undef LOAD_W
#undef LOAD_A
#undef STORE_W
#undef SET_AVC
#undef MFMA_BLOCK

    const int rbase = b * 64 + wid * 16 + quad * 4;
    if (G.W2) {
        // ---- fused attn layer2+3 ----
        constexpr int LDH = 168;
        unsigned short* tile = &WtL[0][0] + wid * 16 * LDH;   // per-wave region
        #pragma unroll
        for (int nt = 0; nt < 10; ++nt) {
            int col = nt * 16 + l15;
            float bv_ = (col < HID) ? G.bias[col] : 0.f;
            #pragma unroll
            for (int r = 0; r < 4; ++r) {
                float v = fmaxf(acc[nt][r] + bv_, 0.f);
                tile[(quad * 4 + r) * LDH + col] = f2bf(v);
            }
        }
        // same-wave RAW through LDS: compiler inserts lgkmcnt; no barrier.
        f32x4 acc2[10];
        #pragma unroll
        for (int nt = 0; nt < 10; ++nt) acc2[nt] = (f32x4){0.f, 0.f, 0.f, 0.f};
        #pragma unroll
        for (int kc = 0; kc < 5; ++kc) {
            short8 av = *(const short8*)&tile[l15 * LDH + kc * 32 + quad * 8];
            #pragma unroll
            for (int nt = 0; nt < 10; ++nt) {
                short8 bv = *(const short8*)(G.W2 + (size_t)(nt * 16 + l15) * 192 + kc * 32 + quad * 8);
                acc2[nt] = __builtin_amdgcn_mfma_f32_16x16x32_bf16(av, bv, acc2[nt], 0, 0, 0);
            }
        }
        float part[4] = {0.f, 0.f, 0.f, 0.f};
        #pragma unroll
        for (int nt = 0; nt < 10; ++nt) {
            int col = nt * 16 + l15;
            float b2 = (col < HID) ? G.bias2[col] : 0.f;
            float vv = (col < HID) ? G.dotv[col] : 0.f;
            #pragma unroll
            for (int r = 0; r < 4; ++r)
                part[r] += fmaxf(acc2[nt][r] + b2, 0.f) * vv;
        }
        #pragma unroll
        for (int r = 0; r < 4; ++r) {
            float p = part[r];
            #pragma unroll
            for (int off = 1; off < 16; off <<= 1) p += __shfl_xor(p, off);
            if (l15 == 0) G.dotout[rbase + r] = p + G.dotb[0];
        }
    } else if (G.dotout) {
        float part[4] = {0.f, 0.f, 0.f, 0.f};
        #pragma unroll
        for (int nt = 0; nt < 10; ++nt) {
            int col = nt * 16 + l15;
            float bv_ = (col < HID) ? G.bias[col] : 0.f;
            float vv = (col < HID) ? G.dotv[col] : 0.f;
            #pragma unroll
            for (int r = 0; r < 4; ++r)
                part[r] += fmaxf(acc[nt][r] + bv_, 0.f) * vv;
        }
        #pragma unroll
        for (int r = 0; r < 4; ++r) {
            float p = part[r];
            #pragma unroll
            for (int off = 1; off < 16; off <<= 1) p += __shfl_xor(p, off);
            if (l15 == 0) G.dotout[rbase + r] = p + G.dotb[0];
        }
    } else {
        #pragma unroll
        for (int nt = 0; nt < 10; ++nt) {
            int col = nt * 16 + l15;
            float bv_ = (G.bias != nullptr && col < HID) ? G.bias[col] : 0.f;
            #pragma unroll
            for (int r = 0; r < 4; ++r) {
                int row = rbase + r;
                float v = acc[nt][r] + bv_;
                if (G.relu) v = fmaxf(v, 0.f);
                G.outh[(size_t)row * G.ldo + col] = f2bf(v);
            }
        }
    }
}

// ---------------------------------------------------------------------------
// span_fused: span layer-1 + span layer-2 + layer-3 dot (unchanged).
// ---------------------------------------------------------------------------
__device__ __forceinline__ void add_bf8(f32x4& A, f32x4& B, u32x4 u) {
    A.x += bf2f(u.x & 0xffff); A.y += bf2f(u.x >> 16);
    A.z += bf2f(u.y & 0xffff); A.w += bf2f(u.y >> 16);
    B.x += bf2f(u.z & 0xffff); B.y += bf2f(u.z >> 16);
    B.z += bf2f(u.w & 0xffff); B.w += bf2f(u.w >> 16);
}
__device__ __forceinline__ void fma_bf8(f32x4& A, f32x4& B, u32x4 u, float w) {
    A.x = fmaf(w, bf2f(u.x & 0xffff), A.x); A.y = fmaf(w, bf2f(u.x >> 16), A.y);
    A.z = fmaf(w, bf2f(u.y & 0xffff), A.z); A.w = fmaf(w, bf2f(u.y >> 16), A.w);
    B.x = fmaf(w, bf2f(u.z & 0xffff), B.x); B.y = fmaf(w, bf2f(u.z >> 16), B.y);
    B.z = fmaf(w, bf2f(u.w & 0xffff), B.z); B.w = fmaf(w, bf2f(u.w >> 16), B.w);
}

__global__ __launch_bounds__(256) void span_fused_kernel(
        const float* __restrict__ attns,
        const int* __restrict__ starts,
        const int* __restrict__ lens,
        const unsigned short* __restrict__ Ps,
        const unsigned short* __restrict__ Pe,
        const unsigned short* __restrict__ Pm,
        const float* __restrict__ PW,           // [9][160], +bs1, zero-padded
        const unsigned short* __restrict__ W2,  // Ws2t [160][192]
        const float* __restrict__ bs2,
        const float* __restrict__ Ws3,
        const float* __restrict__ bs3,
        float* __restrict__ out) {
    constexpr int LDH = 200;                    // 400 B row stride
    __shared__ unsigned short tileAll[4][16 * LDH];
    const int wid = threadIdx.x >> 6;
    const int lane = threadIdx.x & 63;
    const int r = lane & 15;
    const int q = lane >> 4;
    unsigned short* tile = &tileAll[wid][0];
    const int s = blockIdx.x * 64 + wid * 16 + r;

    const int start = starts[s];
    const int len = lens[s];
    const int end = start + len;
    const int width = len + 1;
    const int bucket = (width >= 1) + (width >= 2) + (width >= 3) + (width >= 4) +
                       (width >= 8) + (width >= 16) + (width >= 32) + (width >= 64);

    // serial in-lane softmax (redundant across the 4 q-copies: free)
    int il[10];
    float wgt[10];
    float m = -INFINITY;
    #pragma unroll
    for (int l = 0; l < 10; ++l) {
        int iv = min(start + l, T_TOK - 1);
        il[l] = iv * 160;
        wgt[l] = (l <= len) ? attns[iv] : -INFINITY;
        m = fmaxf(m, wgt[l]);
    }
    float ssum = 0.f;
    #pragma unroll
    for (int l = 0; l < 10; ++l) { wgt[l] = __expf(wgt[l] - m); ssum += wgt[l]; }
    const float inv = 1.f / ssum;
    #pragma unroll
    for (int l = 0; l < 10; ++l) wgt[l] *= inv;

    const unsigned short* ps = Ps + (size_t)start * 160;
    const unsigned short* pe = Pe + (size_t)end * 160;
    const float* pw = PW + bucket * 160;

    // lane (r,q) accumulates chunks c = q+4i of span r's h1 row (16B each).
    #pragma unroll
    for (int i = 0; i < 5; ++i) {
        const int j0 = (q + 4 * i) * 8;
        f32x4 a0 = *(const f32x4*)(pw + j0);
        f32x4 a1 = *(const f32x4*)(pw + j0 + 4);
        add_bf8(a0, a1, *(const u32x4*)(ps + j0));
        add_bf8(a0, a1, *(const u32x4*)(pe + j0));
        #pragma unroll
        for (int l = 0; l < 10; ++l)
            fma_bf8(a0, a1, *(const u32x4*)(Pm + il[l] + j0), wgt[l]);
        u32x4 pk;
        pk.x = (unsigned)f2bf(fmaxf(a0.x, 0.f)) | ((unsigned)f2bf(fmaxf(a0.y, 0.f)) << 16);
        pk.y = (unsigned)f2bf(fmaxf(a0.z, 0.f)) | ((unsigned)f2bf(fmaxf(a0.w, 0.f)) << 16);
        pk.z = (unsigned)f2bf(fmaxf(a1.x, 0.f)) | ((unsigned)f2bf(fmaxf(a1.y, 0.f)) << 16);
        pk.w = (unsigned)f2bf(fmaxf(a1.z, 0.f)) | ((unsigned)f2bf(fmaxf(a1.w, 0.f)) << 16);
        *(u32x4*)&tile[r * LDH + j0] = pk;
    }

    // ---- phase 2: 16x160 GEMM, K=160. same-wave LDS RAW; no barrier. ----
    f32x4 acc[10];
    #pragma unroll
    for (int nt = 0; nt < 10; ++nt) acc[nt] = (f32x4){0.f, 0.f, 0.f, 0.f};
    #pragma unroll
    for (int kc = 0; kc < 5; ++kc) {
        short8 av = *(const short8*)&tile[r * LDH + kc * 32 + q * 8];
        #pragma unroll
        for (int nt = 0; nt < 10; ++nt) {
            short8 bv = *(const short8*)(W2 + (size_t)(nt * 16 + r) * 192 + kc * 32 + q * 8);
            acc[nt] = __builtin_amdgcn_mfma_f32_16x16x32_bf16(av, bv, acc[nt], 0, 0, 0);
        }
    }

    float part[4] = {0.f, 0.f, 0.f, 0.f};
    #pragma unroll
    for (int nt = 0; nt < 10; ++nt) {
        int col = nt * 16 + r;
        float b2 = (col < HID) ? bs2[col] : 0.f;
        float vv = (col < HID) ? Ws3[col] : 0.f;
        #pragma unroll
        for (int rr = 0; rr < 4; ++rr)
            part[rr] += fmaxf(acc[nt][rr] + b2, 0.f) * vv;
    }
    const int rbase = blockIdx.x * 64 + wid * 16 + q * 4;
    #pragma unroll
    for (int rr = 0; rr < 4; ++rr) {
        float p = part[rr];
        #pragma unroll
        for (int off = 1; off < 16; off <<= 1) p += __shfl_xor(p, off);
        if (r == 0) out[rbase + rr] = p + bs3[0];
    }
}

extern "C" void kernel_launch(void* const* d_in, const int* in_sizes, int n_in,
                              void* d_out, int out_size, void* d_ws, size_t ws_size,
                              hipStream_t stream) {
    const float* states = (const float*)d_in[0];
    const float* embeds = (const float*)d_in[1];
    const int* span_starts = (const int*)d_in[2];
    const int* span_lengths = (const int*)d_in[3];
    const float* Wa1 = (const float*)d_in[4];
    const float* ba1 = (const float*)d_in[5];
    const float* Wa2 = (const float*)d_in[6];
    const float* ba2 = (const float*)d_in[7];
    const float* Wa3 = (const float*)d_in[8];
    const float* ba3 = (const float*)d_in[9];
    const float* width_table = (const float*)d_in[10];
    const float* Ws1 = (const float*)d_in[11];
    const float* bs1 = (const float*)d_in[12];
    const float* Ws2 = (const float*)d_in[13];
    const float* bs2 = (const float*)d_in[14];
    const float* Ws3 = (const float*)d_in[15];
    const float* bs3 = (const float*)d_in[16];
    float* out = (float*)d_out;

    // ---- workspace layout ----
    char* w = (char*)d_ws;
    unsigned short* WtA  = (unsigned short*)w;  w += 480 * 1024 * 2;
    unsigned short* WtE  = (unsigned short*)w;  w += 160 * 512 * 2;
    unsigned short* Wa2t = (unsigned short*)w;  w += 160 * 192 * 2;
    unsigned short* Ws2t = (unsigned short*)w;  w += 160 * 192 * 2;
    float* PW    = (float*)w;                   w += 9 * 160 * 4;       // stride 160, +bs1
    float* attns = (float*)w;                   w += 8192 * 4;
    unsigned short* Psh = (unsigned short*)w;   w += (size_t)T_TOK * 160 * 2;   // bf16
    unsigned short* Peh = (unsigned short*)w;   w += (size_t)T_TOK * 160 * 2;   // bf16
    unsigned short* Pmh = (unsigned short*)w;   w += (size_t)T_TOK * 160 * 2;   // bf16
    // No memsets: pad cols (0xAA poison = finite bf16) multiply zeroed W rows.

    // ---- prep: LDS-tiled weight transposes + width proj (+bs1) ----
    // nblk = 3 j-tiles x (Kpad/64) k-tiles
    PrepTab pt;
    pt.g[0] = { Wa1,              WtA,              1024, 1024, 3 * (1024/64) };
    pt.g[1] = { Ws1,              WtA + 160*1024,   1024, 1024, 3 * (1024/64) };
    pt.g[2] = { Ws1 + 1024*150,   WtA + 320*1024,   1024, 1024, 3 * (1024/64) };
    pt.g[3] = { Ws1 + 2048*150,   WtE,               512,  512, 3 * (512/64)  };
    pt.g[4] = { Wa2,              Wa2t,              150,  192, 3 * (192/64)  };
    pt.g[5] = { Ws2,              Ws2t,              150,  192, 3 * (192/64)  };
    pt.wt = width_table; pt.Ws1w = Ws1 + 2560*150; pt.bs1 = bs1; pt.PW = PW;
    int wblk = 0; for (int i = 0; i < 6; ++i) wblk += pt.g[i].nblk;
    prep_kernel<<<wblk + 9, 256, 0, stream>>>(pt);

    GG z = {};

    // ---- fused GEMM1+2 + attn layers 2/3: 4 groups, 512 blocks ----
    GTab t1; t1.ng = 4;
    t1.g[0] = z; t1.g[0].A = states; t1.g[0].lda = 1024; t1.g[0].W = WtA;            t1.g[0].K = 1024;
    t1.g[0].nrb = 128; t1.g[0].bias = ba1;
    t1.g[0].W2 = Wa2t; t1.g[0].bias2 = ba2;
    t1.g[0].dotv = Wa3; t1.g[0].dotb = ba3; t1.g[0].dotout = attns;
    t1.g[1] = z; t1.g[1].A = states; t1.g[1].lda = 1024; t1.g[1].W = WtA + 160*1024; t1.g[1].K = 1024;
    t1.g[1].nrb = 128; t1.g[1].outh = Psh; t1.g[1].ldo = 160;
    t1.g[2] = z; t1.g[2].A = states; t1.g[2].lda = 1024; t1.g[2].W = WtA + 320*1024; t1.g[2].K = 1024;
    t1.g[2].nrb = 128; t1.g[2].outh = Peh; t1.g[2].ldo = 160;
    t1.g[3] = z; t1.g[3].A = embeds; t1.g[3].lda = 512;  t1.g[3].W = WtE;            t1.g[3].K = 512;
    t1.g[3].nrb = 128; t1.g[3].outh = Pmh; t1.g[3].ldo = 160;
    gemm_fused<1, true><<<512, 256, 0, stream>>>(t1);

    // ---- fused span layer1 + layer2 + layer3 dot -> out ----
    span_fused_kernel<<<S_SPAN / 64, 256, 0, stream>>>(attns, span_starts, span_lengths,
                                                       Psh, Peh, Pmh, PW, Ws2t,
                                                       bs2, Ws3, bs3, out);
}

// Round 6
// 166.032 us; speedup vs baseline: 1.3399x; 1.0416x over previous
//
#include <hip/hip_runtime.h>
#include <math.h>

#define T_TOK 8192
#define A_DIM 1024
#define E_DIM 512
#define S_SPAN 32768
#define HID 150

typedef __attribute__((ext_vector_type(8))) short short8;
typedef __attribute__((ext_vector_type(4))) float f32x4;
typedef __attribute__((ext_vector_type(4))) unsigned int u32x4;

__device__ __forceinline__ unsigned short f2bf(float f) {
    unsigned int u = __builtin_bit_cast(unsigned int, f);
    u += 0x7FFFu + ((u >> 16) & 1u);          // RNE
    return (unsigned short)(u >> 16);
}
__device__ __forceinline__ float bf2f(unsigned int h16) {
    unsigned int u = h16 << 16;
    return __builtin_bit_cast(float, u);
}
__device__ __forceinline__ short8 cast8(f32x4 a, f32x4 b) {
    short8 r;
    r[0] = (short)f2bf(a.x); r[1] = (short)f2bf(a.y);
    r[2] = (short)f2bf(a.z); r[3] = (short)f2bf(a.w);
    r[4] = (short)f2bf(b.x); r[5] = (short)f2bf(b.y);
    r[6] = (short)f2bf(b.z); r[7] = (short)f2bf(b.w);
    return r;
}

// Publish-barrier: ds ops retired (lgkmcnt 0) but VMEM loads stay IN FLIGHT
// across the barrier (no vmcnt drain — unlike __syncthreads).
__device__ __forceinline__ void pub_barrier() {
    __builtin_amdgcn_sched_barrier(0);
    asm volatile("s_waitcnt lgkmcnt(0)" ::: "memory");
    __builtin_amdgcn_sched_barrier(0);
    __builtin_amdgcn_s_barrier();
    __builtin_amdgcn_sched_barrier(0);
}

// ---------------------------------------------------------------------------
// prep: weight transposes via LDS 64x64 tiles (coalesced both sides)
// + width projection (+bs1 folded, stride 160, zero-padded).
// ---------------------------------------------------------------------------
struct WConv { const float* src; unsigned short* dst; int K0; int Kpad; int nblk; };
struct PrepTab {
    WConv g[6];
    const float* wt; const float* Ws1w; const float* bs1; float* PW;
};

__global__ __launch_bounds__(256) void prep_kernel(PrepTab tab) {
    __shared__ float tl[64][65];                 // stride 65: conflict-free transpose
    int b = blockIdx.x;
    #pragma unroll
    for (int gi = 0; gi < 6; ++gi) {
        if (b < tab.g[gi].nblk) {
            const int kt   = tab.g[gi].Kpad >> 6;        // k-tiles
            const int j0   = (b / kt) * 64;              // output-row tile base
            const int k0   = (b % kt) * 64;              // k tile base
            const int K0   = tab.g[gi].K0;
            const int Kpad = tab.g[gi].Kpad;
            const int ty = threadIdx.x >> 6, tx = threadIdx.x & 63;
            const float* src = tab.g[gi].src;
            #pragma unroll
            for (int r = 0; r < 16; ++r) {               // coalesced src reads
                int k = k0 + ty * 16 + r;
                int j = j0 + tx;
                tl[ty * 16 + r][tx] = (j < HID && k < K0)
                                      ? src[(size_t)k * HID + j] : 0.f;
            }
            __syncthreads();
            unsigned short* dst = tab.g[gi].dst;
            #pragma unroll
            for (int r = 0; r < 16; ++r) {               // coalesced dst writes
                int j = j0 + ty * 16 + r;
                if (j < 160)
                    dst[(size_t)j * Kpad + k0 + tx] = f2bf(tl[tx][ty * 16 + r]);
            }
            return;
        }
        b -= tab.g[gi].nblk;
    }
    // width projection: 9 blocks. PW row = width_table[b] @ Ws1w + bs1,
    // stride 160 with exact zeros at j>=150.
    int j = threadIdx.x;
    if (j < 160) {
        float acc = 0.f;
        if (j < HID) {
            for (int k = 0; k < 20; ++k)
                acc = fmaf(tab.wt[b * 20 + k], tab.Ws1w[k * HID + j], acc);
            acc += tab.bs1[j];
        }
        tab.PW[b * 160 + j] = acc;
    }
}

// ---------------------------------------------------------------------------
// unified MFMA GEMM, 2-deep pipelined K-loop, STATIC register sets,
// counted-wait barriers. Pairs loop + ODD-nch TAIL (r6 fix): the r3 loop
// replayed a stale chunk when nch was odd (latent — only even nch ran
// before; gemm3's K=192 -> nch=3 would have hit it). The last pair's odd
// phase stores W[nch-1] -> buf0 and sets avc = A[nch-1]; tail just MFMAs.
// Bit-identical accumulation order vs the 1-deep loop.
// ---------------------------------------------------------------------------
struct GG {
    const void* A; int lda;
    const unsigned short* W; int K; int nrb;
    unsigned short* outh; int ldo;
    const float* bias; int relu;
    const float* dotv; const float* dotb; float* dotout;
    const unsigned short* W2; const float* bias2;
};
struct GTab { GG g[4]; int ng; };

template <int TAG, bool AF32>
__global__ __launch_bounds__(256) void gemm_fused(GTab tab) {
    constexpr int LDW = 72;
    __shared__ unsigned short WtL[2][160 * LDW];

    int b = blockIdx.x;
    int gi = 0;
    while (gi < tab.ng - 1 && b >= tab.g[gi].nrb) { b -= tab.g[gi].nrb; ++gi; }
    const GG G = tab.g[gi];

    const int tid = threadIdx.x;
    const int wid = tid >> 6;
    const int lane = tid & 63;
    const int l15 = lane & 15;
    const int quad = lane >> 4;
    const int row0 = b * 64 + wid * 16 + l15;
    const int K = G.K;
    const int nch = K >> 6;                       // 16 (K=1024), 8 (512), 3 (192)
    const float* Af = (const float*)G.A + (size_t)row0 * G.lda;
    const unsigned short* Ah = (const unsigned short*)G.A + (size_t)row0 * G.lda;

    int sn[5], sk[5];
    #pragma unroll
    for (int i = 0; i < 5; ++i) { int u = tid + i * 256; sn[i] = u >> 3; sk[i] = (u & 7) * 8; }

    f32x4 acc[10];
    #pragma unroll
    for (int nt = 0; nt < 10; ++nt) acc[nt] = (f32x4){0.f, 0.f, 0.f, 0.f};

    // named 2-deep register sets — ALL statically indexed (rule #20)
    u32x4 wA[5], wB[5];
    f32x4 fAa[4], fAb[4];
    short8 hAa[2], hAb[2];
    short8 avc0, avc1;

#define LOAD_W(SET, KOFF)                                                     \
    {   _Pragma("unroll")                                                     \
        for (int i = 0; i < 5; ++i)                                           \
            SET[i] = *(const u32x4*)(G.W + (size_t)sn[i] * K + (KOFF) + sk[i]); }
#define LOAD_A(FSET, HSET, KOFF)                                              \
    if (AF32) {                                                               \
        FSET[0] = *(const f32x4*)(Af + (KOFF) + quad * 8);                    \
        FSET[1] = *(const f32x4*)(Af + (KOFF) + quad * 8 + 4);                \
        FSET[2] = *(const f32x4*)(Af + (KOFF) + 32 + quad * 8);               \
        FSET[3] = *(const f32x4*)(Af + (KOFF) + 32 + quad * 8 + 4);           \
    } else {                                                                  \
        HSET[0] = *(const short8*)(Ah + (KOFF) + quad * 8);                   \
        HSET[1] = *(const short8*)(Ah + (KOFF) + 32 + quad * 8);              \
    }
#define STORE_W(SET, BUF)                                                     \
    {   _Pragma("unroll")                                                     \
        for (int i = 0; i < 5; ++i)                                           \
            *(u32x4*)&WtL[BUF][sn[i] * LDW + sk[i]] = SET[i]; }
#define SET_AVC(FSET, HSET)                                                   \
    if (AF32) { avc0 = cast8(FSET[0], FSET[1]); avc1 = cast8(FSET[2], FSET[3]); } \
    else      { avc0 = HSET[0]; avc1 = HSET[1]; }
#define MFMA_BLOCK(BUF)                                                       \
    {   _Pragma("unroll")                                                     \
        for (int nt = 0; nt < 10; ++nt) {                                     \
            short8 bv0 = *(const short8*)&WtL[BUF][(nt * 16 + l15) * LDW + quad * 8]; \
            acc[nt] = __builtin_amdgcn_mfma_f32_16x16x32_bf16(avc0, bv0, acc[nt], 0, 0, 0); \
            short8 bv1 = *(const short8*)&WtL[BUF][(nt * 16 + l15) * LDW + 32 + quad * 8]; \
            acc[nt] = __builtin_amdgcn_mfma_f32_16x16x32_bf16(avc1, bv1, acc[nt], 0, 0, 0); \
        } }

    // ---- prologue: issue chunk 0 AND chunk 1 loads before any wait ----
    LOAD_W(wA, 0);
    LOAD_A(fAa, hAa, 0);
    LOAD_W(wB, 64);
    LOAD_A(fAb, hAb, 64);
    STORE_W(wA, 0);
    SET_AVC(fAa, hAa);
    pub_barrier();

    for (int c = 0; c + 1 < nch; c += 2) {
        // ---- even chunk c (LDS buf 0) ----
        const bool mA = (c + 2 < nch);
        if (mA) {
            const int kn = (c + 2) << 6;
            LOAD_W(wA, kn);
            LOAD_A(fAa, hAa, kn);
        }
        STORE_W(wB, 1);                     // chunk c+1: loaded a full chunk ago
        MFMA_BLOCK(0);                      // chunk c
        SET_AVC(fAb, hAb);                  // A operand for chunk c+1
        pub_barrier();

        // ---- odd chunk c+1 (LDS buf 1) ----
        const bool mB = (c + 3 < nch);
        if (mB) {
            const int kn = (c + 3) << 6;
            LOAD_W(wB, kn);
            LOAD_A(fAb, hAb, kn);
        }
        if (mA) STORE_W(wA, 0);             // chunk c+2
        MFMA_BLOCK(1);                      // chunk c+1
        if (mA) SET_AVC(fAa, hAa);          // A operand for chunk c+2
        pub_barrier();
    }
    if (nch & 1) {
        // tail chunk nch-1: stored into buf0 at the last pair's odd phase,
        // avc already = A[nch-1]; trailing pub_barrier ordered the stores.
        MFMA_BLOCK(0);
    }

#undef LOAD_W
#undef LOAD_A
#undef STORE_W
#undef SET_AVC
#undef MFMA_BLOCK

    const int rbase = b * 64 + wid * 16 + quad * 4;
    if (G.W2) {
        // ---- fused attn layer2+3 ----
        constexpr int LDH = 168;
        unsigned short* tile = &WtL[0][0] + wid * 16 * LDH;   // per-wave region
        #pragma unroll
        for (int nt = 0; nt < 10; ++nt) {
            int col = nt * 16 + l15;
            float bv_ = (col < HID) ? G.bias[col] : 0.f;
            #pragma unroll
            for (int r = 0; r < 4; ++r) {
                float v = fmaxf(acc[nt][r] + bv_, 0.f);
                tile[(quad * 4 + r) * LDH + col] = f2bf(v);
            }
        }
        // same-wave RAW through LDS: compiler inserts lgkmcnt; no barrier.
        f32x4 acc2[10];
        #pragma unroll
        for (int nt = 0; nt < 10; ++nt) acc2[nt] = (f32x4){0.f, 0.f, 0.f, 0.f};
        #pragma unroll
        for (int kc = 0; kc < 5; ++kc) {
            short8 av = *(const short8*)&tile[l15 * LDH + kc * 32 + quad * 8];
            #pragma unroll
            for (int nt = 0; nt < 10; ++nt) {
                short8 bv = *(const short8*)(G.W2 + (size_t)(nt * 16 + l15) * 192 + kc * 32 + quad * 8);
                acc2[nt] = __builtin_amdgcn_mfma_f32_16x16x32_bf16(av, bv, acc2[nt], 0, 0, 0);
            }
        }
        float part[4] = {0.f, 0.f, 0.f, 0.f};
        #pragma unroll
        for (int nt = 0; nt < 10; ++nt) {
            int col = nt * 16 + l15;
            float b2 = (col < HID) ? G.bias2[col] : 0.f;
            float vv = (col < HID) ? G.dotv[col] : 0.f;
            #pragma unroll
            for (int r = 0; r < 4; ++r)
                part[r] += fmaxf(acc2[nt][r] + b2, 0.f) * vv;
        }
        #pragma unroll
        for (int r = 0; r < 4; ++r) {
            float p = part[r];
            #pragma unroll
            for (int off = 1; off < 16; off <<= 1) p += __shfl_xor(p, off);
            if (l15 == 0) G.dotout[rbase + r] = p + G.dotb[0];
        }
    } else if (G.dotout) {
        float part[4] = {0.f, 0.f, 0.f, 0.f};
        #pragma unroll
        for (int nt = 0; nt < 10; ++nt) {
            int col = nt * 16 + l15;
            float bv_ = (col < HID) ? G.bias[col] : 0.f;
            float vv = (col < HID) ? G.dotv[col] : 0.f;
            #pragma unroll
            for (int r = 0; r < 4; ++r)
                part[r] += fmaxf(acc[nt][r] + bv_, 0.f) * vv;
        }
        #pragma unroll
        for (int r = 0; r < 4; ++r) {
            float p = part[r];
            #pragma unroll
            for (int off = 1; off < 16; off <<= 1) p += __shfl_xor(p, off);
            if (l15 == 0) G.dotout[rbase + r] = p + G.dotb[0];
        }
    } else {
        #pragma unroll
        for (int nt = 0; nt < 10; ++nt) {
            int col = nt * 16 + l15;
            float bv_ = (G.bias != nullptr && col < HID) ? G.bias[col] : 0.f;
            #pragma unroll
            for (int r = 0; r < 4; ++r) {
                int row = rbase + r;
                float v = acc[nt][r] + bv_;
                if (G.relu) v = fmaxf(v, 0.f);
                G.outh[(size_t)row * G.ldo + col] = f2bf(v);
            }
        }
    }
}

// ---------------------------------------------------------------------------
// span layer-1 (r0 structure, 2048 blocks -> 32 waves/CU of gather-latency
// hiding): one span per 16-lane group (4/wave, 16/block). PW has bs1 folded
// (stride 160). Writes SH1 [S][192] bf16.
// ---------------------------------------------------------------------------
__global__ __launch_bounds__(256) void span_l1_kernel(const float* __restrict__ attns,
                                                      const int* __restrict__ starts,
                                                      const int* __restrict__ lens,
                                                      const unsigned short* __restrict__ Ps,
                                                      const unsigned short* __restrict__ Pe,
                                                      const unsigned short* __restrict__ Pm,
                                                      const float* __restrict__ PW,
                                                      unsigned short* __restrict__ SH1) {
    const int wid = threadIdx.x >> 6;
    const int lane = threadIdx.x & 63;
    const int grp = lane >> 4;
    const int hl = lane & 15;
    const int gbase = lane & 48;
    const int s = blockIdx.x * 16 + wid * 4 + grp;
    const int start = starts[s];
    const int len = lens[s];

    const int iv = min(start + hl, T_TOK - 1);
    float a = (hl <= len) ? attns[iv] : -INFINITY;
    float m = a;
    #pragma unroll
    for (int off = 8; off; off >>= 1) m = fmaxf(m, __shfl_xor(m, off));
    float e = (hl <= len) ? __expf(a - m) : 0.f;
    float ssum = e;
    #pragma unroll
    for (int off = 8; off; off >>= 1) ssum += __shfl_xor(ssum, off);
    float wv = e / ssum;

    float wl[10]; int il[10];
    #pragma unroll
    for (int l = 0; l < 10; ++l) {
        wl[l] = __shfl(wv, gbase + l);
        il[l] = __shfl(iv, gbase + l);
    }

    const int end = start + len;
    const int width = len + 1;
    const int bucket = (width >= 1) + (width >= 2) + (width >= 3) + (width >= 4) +
                       (width >= 8) + (width >= 16) + (width >= 32) + (width >= 64);

    const unsigned short* ps = Ps + (size_t)start * 160;
    const unsigned short* pe = Pe + (size_t)end * 160;
    const float* pw = PW + bucket * 160;

    for (int p = hl; p < 75; p += 16) {
        const int j = 2 * p;
        unsigned int u0 = *(const unsigned int*)(ps + j);
        unsigned int u1 = *(const unsigned int*)(pe + j);
        float a0 = pw[j]     + bf2f(u0 & 0xffff) + bf2f(u1 & 0xffff);
        float a1 = pw[j + 1] + bf2f(u0 >> 16)    + bf2f(u1 >> 16);
        #pragma unroll
        for (int l = 0; l < 10; ++l) {
            unsigned int um = *(const unsigned int*)(Pm + (size_t)il[l] * 160 + j);
            a0 = fmaf(wl[l], bf2f(um & 0xffff), a0);
            a1 = fmaf(wl[l], bf2f(um >> 16), a1);
        }
        unsigned int packed = (unsigned int)f2bf(fmaxf(a0, 0.f)) |
                              ((unsigned int)f2bf(fmaxf(a1, 0.f)) << 16);
        *(unsigned int*)(SH1 + (size_t)s * 192 + j) = packed;
    }
}

extern "C" void kernel_launch(void* const* d_in, const int* in_sizes, int n_in,
                              void* d_out, int out_size, void* d_ws, size_t ws_size,
                              hipStream_t stream) {
    const float* states = (const float*)d_in[0];
    const float* embeds = (const float*)d_in[1];
    const int* span_starts = (const int*)d_in[2];
    const int* span_lengths = (const int*)d_in[3];
    const float* Wa1 = (const float*)d_in[4];
    const float* ba1 = (const float*)d_in[5];
    const float* Wa2 = (const float*)d_in[6];
    const float* ba2 = (const float*)d_in[7];
    const float* Wa3 = (const float*)d_in[8];
    const float* ba3 = (const float*)d_in[9];
    const float* width_table = (const float*)d_in[10];
    const float* Ws1 = (const float*)d_in[11];
    const float* bs1 = (const float*)d_in[12];
    const float* Ws2 = (const float*)d_in[13];
    const float* bs2 = (const float*)d_in[14];
    const float* Ws3 = (const float*)d_in[15];
    const float* bs3 = (const float*)d_in[16];
    float* out = (float*)d_out;

    // ---- workspace layout ----
    char* w = (char*)d_ws;
    unsigned short* WtA  = (unsigned short*)w;  w += 480 * 1024 * 2;
    unsigned short* WtE  = (unsigned short*)w;  w += 160 * 512 * 2;
    unsigned short* Wa2t = (unsigned short*)w;  w += 160 * 192 * 2;
    unsigned short* Ws2t = (unsigned short*)w;  w += 160 * 192 * 2;
    float* PW    = (float*)w;                   w += 9 * 160 * 4;       // stride 160, +bs1
    float* attns = (float*)w;                   w += 8192 * 4;
    unsigned short* Psh = (unsigned short*)w;   w += (size_t)T_TOK * 160 * 2;   // bf16
    unsigned short* Peh = (unsigned short*)w;   w += (size_t)T_TOK * 160 * 2;   // bf16
    unsigned short* Pmh = (unsigned short*)w;   w += (size_t)T_TOK * 160 * 2;   // bf16
    unsigned short* SH1 = (unsigned short*)w;   w += (size_t)S_SPAN * 192 * 2;  // bf16
    // No memsets: pad cols (0xAA poison = finite bf16) multiply zeroed W rows.

    // ---- prep: LDS-tiled weight transposes + width proj (+bs1) ----
    PrepTab pt;
    pt.g[0] = { Wa1,              WtA,              1024, 1024, 3 * (1024/64) };
    pt.g[1] = { Ws1,              WtA + 160*1024,   1024, 1024, 3 * (1024/64) };
    pt.g[2] = { Ws1 + 1024*150,   WtA + 320*1024,   1024, 1024, 3 * (1024/64) };
    pt.g[3] = { Ws1 + 2048*150,   WtE,               512,  512, 3 * (512/64)  };
    pt.g[4] = { Wa2,              Wa2t,              150,  192, 3 * (192/64)  };
    pt.g[5] = { Ws2,              Ws2t,              150,  192, 3 * (192/64)  };
    pt.wt = width_table; pt.Ws1w = Ws1 + 2560*150; pt.bs1 = bs1; pt.PW = PW;
    int wblk = 0; for (int i = 0; i < 6; ++i) wblk += pt.g[i].nblk;
    prep_kernel<<<wblk + 9, 256, 0, stream>>>(pt);

    GG z = {};

    // ---- fused GEMM1+2 + attn layers 2/3: 4 groups, 512 blocks ----
    GTab t1; t1.ng = 4;
    t1.g[0] = z; t1.g[0].A = states; t1.g[0].lda = 1024; t1.g[0].W = WtA;            t1.g[0].K = 1024;
    t1.g[0].nrb = 128; t1.g[0].bias = ba1;
    t1.g[0].W2 = Wa2t; t1.g[0].bias2 = ba2;
    t1.g[0].dotv = Wa3; t1.g[0].dotb = ba3; t1.g[0].dotout = attns;
    t1.g[1] = z; t1.g[1].A = states; t1.g[1].lda = 1024; t1.g[1].W = WtA + 160*1024; t1.g[1].K = 1024;
    t1.g[1].nrb = 128; t1.g[1].outh = Psh; t1.g[1].ldo = 160;
    t1.g[2] = z; t1.g[2].A = states; t1.g[2].lda = 1024; t1.g[2].W = WtA + 320*1024; t1.g[2].K = 1024;
    t1.g[2].nrb = 128; t1.g[2].outh = Peh; t1.g[2].ldo = 160;
    t1.g[3] = z; t1.g[3].A = embeds; t1.g[3].lda = 512;  t1.g[3].W = WtE;            t1.g[3].K = 512;
    t1.g[3].nrb = 128; t1.g[3].outh = Pmh; t1.g[3].ldo = 160;
    gemm_fused<1, true><<<512, 256, 0, stream>>>(t1);

    // ---- span layer1 -> SH1 (bf16), 16 spans/block, 2048 blocks ----
    span_l1_kernel<<<S_SPAN / 16, 256, 0, stream>>>(attns, span_starts, span_lengths,
                                                    Psh, Peh, Pmh, PW, SH1);

    // ---- span layer2 + fused layer3 dot -> out (K=192, odd-nch tail path) ----
    GTab t3; t3.ng = 1;
    t3.g[0] = z; t3.g[0].A = SH1; t3.g[0].lda = 192; t3.g[0].W = Ws2t; t3.g[0].K = 192;
    t3.g[0].nrb = 512; t3.g[0].bias = bs2; t3.g[0].dotv = Ws3; t3.g[0].dotb = bs3; t3.g[0].dotout = out;
    gemm_fused<3, false><<<512, 256, 0, stream>>>(t3);
}